// Round 1
// baseline (209.249 us; speedup 1.0000x reference)
//
#include <hip/hip_runtime.h>

#define D 64
#define EPSV 1e-9f

// --- Kernel 1: CSR row offsets from sorted edge_dst via per-node lower_bound ---
__global__ void build_offsets(const int* __restrict__ edge_dst,
                              int* __restrict__ row_off,
                              int n_nodes, int n_edges) {
    int n = blockIdx.x * blockDim.x + threadIdx.x;
    if (n > n_nodes) return;
    int lo = 0, hi = n_edges;
    while (lo < hi) {
        int mid = (lo + hi) >> 1;
        if (edge_dst[mid] < n) lo = mid + 1; else hi = mid;
    }
    row_off[n] = lo;  // first edge with dst >= n
}

// --- Kernel 2: 64x64 transpose (so layer kernel reads W coalesced) ---
__global__ void transpose64(const float* __restrict__ W, float* __restrict__ WT) {
    int idx = blockIdx.x * blockDim.x + threadIdx.x;
    if (idx >= D * D) return;
    int r = idx >> 6, c = idx & 63;
    WT[c * D + r] = W[r * D + c];
}

// --- Kernel 3: one GNN layer. One wave (64 lanes) per node; lane = feature dim.
// msg[n,d] = (sum_e w_e * feats[src_e, d]) / (sum_e w_e + eps)
// out[n,d] = relu( sum_k feats[n,k]*W0[d,k] + b0[d] + sum_k msg[k]*W1[d,k] + b1[d] )
__global__ __launch_bounds__(256) void layer_kernel(
    const float* __restrict__ feats_in,
    const int*   __restrict__ row_off,
    const int*   __restrict__ edge_src,
    const float* __restrict__ edge_w,
    const float* __restrict__ W0T,  // [k][d] = W0[d][k]
    const float* __restrict__ b0,
    const float* __restrict__ W1T,  // [k][d] = W1[d][k]
    const float* __restrict__ b1,
    float* __restrict__ feats_out,
    int n_nodes)
{
    __shared__ float lds_f[4][D];
    __shared__ float lds_m[4][D];

    const int lane = threadIdx.x & 63;
    const int wib  = threadIdx.x >> 6;          // wave-in-block, 0..3
    int node = blockIdx.x * 4 + wib;
    if (node >= n_nodes) node = n_nodes - 1;    // keep wave alive for __syncthreads; dup write is identical data
    node = __builtin_amdgcn_readfirstlane(node); // force wave-uniform -> scalar edge loads

    const int s = row_off[node];
    const int e = row_off[node + 1];

    float acc  = 0.0f;   // sum_e w * feats[src, lane]
    float wsum = 0.0f;   // sum_e w  (same in all lanes)
    for (int i = s; i < e; ++i) {
        const float w = edge_w[i];
        const int src = edge_src[i];
        acc = fmaf(w, feats_in[src * D + lane], acc);
        wsum += w;
    }
    const float msg  = acc / (wsum + EPSV);
    const float self = feats_in[node * D + lane];

    lds_f[wib][lane] = self;
    lds_m[wib][lane] = msg;
    __syncthreads();

    float o = b0[lane] + b1[lane];
    #pragma unroll
    for (int k = 0; k < D; ++k) {
        o = fmaf(lds_f[wib][k], W0T[k * D + lane], o);
        o = fmaf(lds_m[wib][k], W1T[k * D + lane], o);
    }
    feats_out[node * D + lane] = fmaxf(o, 0.0f);
}

extern "C" void kernel_launch(void* const* d_in, const int* in_sizes, int n_in,
                              void* d_out, int out_size, void* d_ws, size_t ws_size,
                              hipStream_t stream) {
    const float* node_feats = (const float*)d_in[0];
    const int*   edge_src   = (const int*)  d_in[1];
    const int*   edge_dst   = (const int*)  d_in[2];
    const float* edge_w     = (const float*)d_in[3];
    const float* W0         = (const float*)d_in[4];
    const float* b0         = (const float*)d_in[5];
    const float* W1         = (const float*)d_in[6];
    const float* b1         = (const float*)d_in[7];
    float* out = (float*)d_out;

    const int n_nodes = in_sizes[0] / D;   // 50000
    const int n_edges = in_sizes[1];       // 800000

    // workspace layout (all 256B-aligned)
    char* ws = (char*)d_ws;
    int*   row_off   = (int*)ws;                      // (n_nodes+1) ints  (<= 200004 B)
    float* W0T       = (float*)(ws + 204800);         // 16384 B
    float* W1T       = (float*)(ws + 221184);         // 16384 B
    float* feats_mid = (float*)(ws + 237568);         // n_nodes*D*4 = 12.8 MB

    build_offsets<<<(n_nodes + 1 + 255) / 256, 256, 0, stream>>>(edge_dst, row_off, n_nodes, n_edges);
    transpose64<<<(D * D + 255) / 256, 256, 0, stream>>>(W0, W0T);
    transpose64<<<(D * D + 255) / 256, 256, 0, stream>>>(W1, W1T);

    const int grid = (n_nodes + 3) / 4;  // 4 nodes per 256-thread block
    layer_kernel<<<grid, 256, 0, stream>>>(node_feats, row_off, edge_src, edge_w,
                                           W0T, b0, W1T, b1, feats_mid, n_nodes);
    layer_kernel<<<grid, 256, 0, stream>>>(feats_mid, row_off, edge_src, edge_w,
                                           W0T, b0, W1T, b1, out, n_nodes);
}